// Round 9
// baseline (321.937 us; speedup 1.0000x reference)
//
#include <hip/hip_runtime.h>

typedef __fp16 mf16x8 __attribute__((ext_vector_type(8)));
typedef float f32x4 __attribute__((ext_vector_type(4)));

#define Tt 187
#define IST 189   // ibuf row stride (f32)
#define L2E 1.44269504088896340736f

// ---- paired activations on PRE-SCALED pre-activations ----
// weights/bias rows are pre-multiplied: i,f,o by -L2E ; g by +2*L2E.
__device__ __forceinline__ void psigm2(float xa, float xb, float& sa, float& sb) {
  float da = 1.f + __builtin_amdgcn_exp2f(xa);
  float db = 1.f + __builtin_amdgcn_exp2f(xb);
  float rp = __builtin_amdgcn_rcpf(da * db);
  sa = db * rp;
  sb = da * rp;
}
__device__ __forceinline__ void ptanh2(float xa, float xb, float& ta, float& tb) {
  float da = 1.f + __builtin_amdgcn_exp2f(xa);
  float db = 1.f + __builtin_amdgcn_exp2f(xb);
  float rp = __builtin_amdgcn_rcpf(da * db);
  float m2 = -2.f * rp;
  ta = fmaf(db, m2, 1.f);
  tb = fmaf(da, m2, 1.f);
}
__device__ __forceinline__ void ptanh_sigm(float xg, float xo, float& tg, float& so) {
  float dg = 1.f + __builtin_amdgcn_exp2f(xg);
  float dn = 1.f + __builtin_amdgcn_exp2f(xo);
  float rp = __builtin_amdgcn_rcpf(dg * dn);
  tg = fmaf(dn, -2.f * rp, 1.f);
  so = dg * rp;
}
__device__ __forceinline__ void ctanh2(float ca, float cb, float& ta, float& tb) {
  float xa = __builtin_amdgcn_fmed3f(ca, -16.f, 16.f) * (2.f * L2E);
  float xb = __builtin_amdgcn_fmed3f(cb, -16.f, 16.f) * (2.f * L2E);
  ptanh2(xa, xb, ta, tb);
}

__device__ __forceinline__ unsigned int pkbits(float lo, float hi) {
  return __builtin_bit_cast(unsigned int, __builtin_amdgcn_cvt_pkrtz(lo, hi));
}
// B fragment from this lane's own hn[5] (+ x in slot element 5): k-slot 8g+jt <-> unit 4jt+g
__device__ __forceinline__ mf16x8 mkbf(const float* hn, float xsel) {
  union { unsigned int u[4]; mf16x8 v; } cv;
  cv.u[0] = pkbits(hn[0], hn[1]);
  cv.u[1] = pkbits(hn[2], hn[3]);
  cv.u[2] = pkbits(hn[4], xsel);
  cv.u[3] = 0u;
  return cv.v;
}

// Stage one layer's weights into per-lane MFMA fragments, PRE-SCALED per gate.
__device__ __forceinline__ void stage_layer(
    const float* __restrict__ Wih, const float* __restrict__ Whh,
    const float* __restrict__ bih, const float* __restrict__ bhh,
    int m, int g, mf16x8* A, f32x4* Bias)
{
  const int gateA = m & 3;
  const float scA = (gateA == 2) ? (2.f * L2E) : -L2E;   // gate g vs i/f/o
#pragma unroll
  for (int jt = 0; jt < 5; ++jt) {
    const int unitA = 4 * jt + (m >> 2);
    const int trow = gateA * 20 + unitA;          // torch row in [4H]
    union { __fp16 h[8]; mf16x8 v; } av;
#pragma unroll
    for (int kk = 0; kk < 8; ++kk) {
      const int s = 8 * g + kk;
      float w = 0.f;
      if (kk < 5)       w = Whh[trow * 20 + 4 * kk + g];
      else if (s == 21) w = Wih[trow];
      av.h[kk] = (__fp16)(w * scA);
    }
    A[jt] = av.v;
    const int u = 4 * jt + g;
    f32x4 bv;
#pragma unroll
    for (int i = 0; i < 4; ++i) {
      const float sc = (i == 2) ? (2.f * L2E) : -L2E;
      bv[i] = (bih[i * 20 + u] + bhh[i * 20 + u]) * sc;
    }
    Bias[jt] = bv;
  }
}

#define GPAIR(accA, accB, JA, JB) do {                     \
    float iA, fA, iB, fB, gA, gB, oA, oB, tA, tB;          \
    psigm2((accA)[0], (accA)[1], iA, fA);                  \
    psigm2((accB)[0], (accB)[1], iB, fB);                  \
    ptanh2((accA)[2], (accB)[2], gA, gB);                  \
    psigm2((accA)[3], (accB)[3], oA, oB);                  \
    float cA = fmaf(fA, c_[JA], iA * gA);                  \
    float cB = fmaf(fB, c_[JB], iB * gB);                  \
    c_[JA] = cA; c_[JB] = cB;                              \
    ctanh2(cA, cB, tA, tB);                                \
    hn[JA] = oA * tA; hn[JB] = oB * tB;                    \
  } while (0)

#define GLAST(acc4) do {                                               \
    float i4, f4, g4, o4;                                              \
    psigm2((acc4)[0], (acc4)[1], i4, f4);                              \
    ptanh_sigm((acc4)[2], (acc4)[3], g4, o4);                          \
    float c4 = fmaf(f4, c_[4], i4 * g4);                               \
    c_[4] = c4;                                                        \
    float s4 = __builtin_amdgcn_fmed3f(c4, -16.f, 16.f) * (2.f * L2E); \
    float d4 = 1.f + __builtin_amdgcn_exp2f(s4);                       \
    float t4 = fmaf(__builtin_amdgcn_rcpf(d4), -2.f, 1.f);             \
    hn[4] = o4 * t4;                                                   \
  } while (0)

// gate block for one chain's 5 units (intra-chain rcp-pairing only)
__device__ __forceinline__ void gates5(const f32x4* a, float* c_, float* hn) {
  GPAIR(a[0], a[1], 0, 1);
  GPAIR(a[2], a[3], 2, 3);
  GLAST(a[4]);
}

// One LSTM step for TWO fully independent chains: 10 MFMAs, then both gate blocks.
#define STEP2(A, B, bfA, bfB) do {                                               \
    f32x4 aA[5], aB[5];                                                          \
    _Pragma("unroll")                                                            \
    for (int jt = 0; jt < 5; ++jt) {                                             \
      aA[jt] = __builtin_amdgcn_mfma_f32_16x16x32_f16((A)[jt], bfA, (B)[jt], 0, 0, 0); \
      aB[jt] = __builtin_amdgcn_mfma_f32_16x16x32_f16((A)[jt], bfB, (B)[jt], 0, 0, 0); \
    }                                                                            \
    gates5(aA, cA_, hnA);                                                        \
    gates5(aB, cB_, hnB);                                                        \
  } while (0)

extern "C" __global__ __launch_bounds__(64) void lstm_fused(
    const float* __restrict__ inp,  const float* __restrict__ Wih1,
    const float* __restrict__ Whh1, const float* __restrict__ bih1,
    const float* __restrict__ bhh1, const float* __restrict__ Wih2,
    const float* __restrict__ Whh2, const float* __restrict__ bih2,
    const float* __restrict__ bhh2, const float* __restrict__ Wl,
    const float* __restrict__ bl,   float* __restrict__ out, int Btot)
{
  __shared__ __align__(16) float ibuf[32 * IST];   // input tile, 2 chains

  const int lane = threadIdx.x;
  const int r = lane & 15;      // batch row within each 16-row tile
  const int g = lane >> 4;      // k-chunk / unit-group id
  const int row0 = blockIdx.x * 32;

  // stage input tile (32 rows), coalesced
  {
    const float* src = inp + (size_t)row0 * Tt;
    for (int i = lane; i < 32 * Tt; i += 64) {
      int rr = i / Tt, t = i - rr * Tt;
      ibuf[rr * IST + t] = src[i];
    }
  }

  mf16x8 A1[5]; f32x4 B1[5];
  stage_layer(Wih1, Whh1, bih1, bhh1, r, g, A1, B1);

  float cA_[5], cB_[5], hnA[5], hnB[5];
#pragma unroll
  for (int jt = 0; jt < 5; ++jt) { cA_[jt] = cB_[jt] = 0.f; hnA[jt] = hnB[jt] = 0.f; }

  __syncthreads();

  // ================= encoder: two independent chains =================
  float xtA = ibuf[r * IST];
  float xtB = ibuf[(16 + r) * IST];
  for (int t = 0; t < Tt; ++t) {
    mf16x8 bfA = mkbf(hnA, (g == 2) ? xtA : 0.f);
    mf16x8 bfB = mkbf(hnB, (g == 2) ? xtB : 0.f);
    STEP2(A1, B1, bfA, bfB);
    if (t + 1 < Tt) {
      xtA = ibuf[r * IST + t + 1];
      xtB = ibuf[(16 + r) * IST + t + 1];
    }
  }

  // ================= log_softmax(h_e), both chains =================
  {
    float mA = hnA[0], mB = hnB[0];
#pragma unroll
    for (int jt = 1; jt < 5; ++jt) { mA = fmaxf(mA, hnA[jt]); mB = fmaxf(mB, hnB[jt]); }
    mA = fmaxf(mA, __shfl_xor(mA, 16, 64)); mB = fmaxf(mB, __shfl_xor(mB, 16, 64));
    mA = fmaxf(mA, __shfl_xor(mA, 32, 64)); mB = fmaxf(mB, __shfl_xor(mB, 32, 64));
    float sA = 0.f, sB = 0.f;
#pragma unroll
    for (int jt = 0; jt < 5; ++jt) {
      sA += __builtin_amdgcn_exp2f((hnA[jt] - mA) * L2E);
      sB += __builtin_amdgcn_exp2f((hnB[jt] - mB) * L2E);
    }
    sA += __shfl_xor(sA, 16, 64); sB += __shfl_xor(sB, 16, 64);
    sA += __shfl_xor(sA, 32, 64); sB += __shfl_xor(sB, 32, 64);
    const float lseA = mA + 0.69314718055994530942f * __builtin_amdgcn_logf(sA);
    const float lseB = mB + 0.69314718055994530942f * __builtin_amdgcn_logf(sB);
    float* out2 = out + (size_t)Btot * Tt;
#pragma unroll
    for (int jt = 0; jt < 5; ++jt) {
      out2[(size_t)(row0 + r) * 20 + 4 * jt + g]      = hnA[jt] - lseA;
      out2[(size_t)(row0 + 16 + r) * 20 + 4 * jt + g] = hnB[jt] - lseB;
    }
  }

  // ================= decoder =================
  mf16x8 A2[5]; f32x4 B2[5];
  stage_layer(Wih2, Whh2, bih2, bhh2, r, g, A2, B2);
  float wl[5];
#pragma unroll
  for (int jt = 0; jt < 5; ++jt) wl[jt] = Wl[4 * jt + g] * -L2E;  // pre-scaled
  const float blv = bl[0] * -L2E;

  float otA = 0.f, otB = 0.f;
  for (int s = 0; s < Tt; ++s) {
    mf16x8 bfA = mkbf(hnA, (g == 2) ? otA : 0.f);
    mf16x8 bfB = mkbf(hnB, (g == 2) ? otB : 0.f);
    STEP2(A2, B2, bfA, bfB);
    float pA = fmaf(hnA[0], wl[0], blv);
    float pB = fmaf(hnB[0], wl[0], blv);
#pragma unroll
    for (int jt = 1; jt < 5; ++jt) {
      pA = fmaf(hnA[jt], wl[jt], pA);
      pB = fmaf(hnB[jt], wl[jt], pB);
    }
    pA += __shfl_xor(pA, 16, 64); pB += __shfl_xor(pB, 16, 64);
    pA += __shfl_xor(pA, 32, 64); pB += __shfl_xor(pB, 32, 64);
    psigm2(pA, pB, otA, otB);    // pre-scaled; single cross-chain join per step
    if (g == 0) {
      out[(size_t)(row0 + r) * Tt + (186 - s)]      = otA;   // pre-flipped
      out[(size_t)(row0 + 16 + r) * Tt + (186 - s)] = otB;
    }
  }
}

extern "C" void kernel_launch(void* const* d_in, const int* in_sizes, int n_in,
                              void* d_out, int out_size, void* d_ws, size_t ws_size,
                              hipStream_t stream) {
  const float* inp  = (const float*)d_in[0];
  const float* Wih1 = (const float*)d_in[1];
  const float* Whh1 = (const float*)d_in[2];
  const float* bih1 = (const float*)d_in[3];
  const float* bhh1 = (const float*)d_in[4];
  const float* Wih2 = (const float*)d_in[5];
  const float* Whh2 = (const float*)d_in[6];
  const float* bih2 = (const float*)d_in[7];
  const float* bhh2 = (const float*)d_in[8];
  const float* Wl   = (const float*)d_in[9];
  const float* bl   = (const float*)d_in[10];

  const int Btot = in_sizes[0] / Tt;   // 32768
  dim3 grid(Btot / 32), block(64);
  hipLaunchKernelGGL(lstm_fused, grid, block, 0, stream,
                     inp, Wih1, Whh1, bih1, bhh1, Wih2, Whh2, bih2, bhh2, Wl, bl,
                     (float*)d_out, Btot);
}

// Round 10
// 298.676 us; speedup vs baseline: 1.0779x; 1.0779x over previous
//
#include <hip/hip_runtime.h>

typedef __fp16 mf16x8 __attribute__((ext_vector_type(8)));
typedef float f32x4 __attribute__((ext_vector_type(4)));

#define Tt 187
#define IST 189   // ibuf row stride (f32)
#define L2E 1.44269504088896340736f

__device__ __forceinline__ float ex2(float x)  { return __builtin_amdgcn_exp2f(x); }
__device__ __forceinline__ float rcp_(float x) { return __builtin_amdgcn_rcpf(x); }

// ---- 4-way rcp-shared activations on PRE-SCALED pre-activations ----
// weights/bias pre-multiplied: i,f,o by -L2E ; g by +2*L2E.
// sigm(x) = rcp(1 + exp2(x')) ; tanh(x) = 1 - 2*rcp(1 + exp2(x''))

// 4 sigmoids, one rcp
__device__ __forceinline__ void sigm4(float x0, float x1, float x2, float x3,
                                      float& s0, float& s1, float& s2, float& s3) {
  float d0 = 1.f + ex2(x0), d1 = 1.f + ex2(x1);
  float d2 = 1.f + ex2(x2), d3 = 1.f + ex2(x3);
  float p01 = d0 * d1, p23 = d2 * d3;
  float rp = rcp_(p01 * p23);
  float q01 = p23 * rp, q23 = p01 * rp;   // 1/p01, 1/p23
  s0 = d1 * q01; s1 = d0 * q01;
  s2 = d3 * q23; s3 = d2 * q23;
}
// 2 tanh + 2 sigmoids, one rcp
__device__ __forceinline__ void tanh2sigm2(float xg0, float xg1, float xo0, float xo1,
                                           float& g0, float& g1, float& s0, float& s1) {
  float dg0 = 1.f + ex2(xg0), dg1 = 1.f + ex2(xg1);
  float do0 = 1.f + ex2(xo0), do1 = 1.f + ex2(xo1);
  float pg = dg0 * dg1, po = do0 * do1;
  float rp = rcp_(pg * po);
  float qg = po * rp, qo = pg * rp;       // 1/pg, 1/po
  s0 = do1 * qo; s1 = do0 * qo;
  g0 = fmaf(dg1 * qg, -2.f, 1.f);
  g1 = fmaf(dg0 * qg, -2.f, 1.f);
}
// 1 tanh + 3 sigmoids (unit 4's i,f,o,g), one rcp
__device__ __forceinline__ void tanh1sigm3(float xg, float xi, float xf, float xo,
                                           float& g4, float& i4, float& f4, float& o4) {
  float dg = 1.f + ex2(xg), di = 1.f + ex2(xi);
  float df = 1.f + ex2(xf), dn = 1.f + ex2(xo);
  float pif = di * df, pgo = dg * dn;
  float rp = rcp_(pif * pgo);
  float qif = pgo * rp, qgo = pif * rp;   // 1/pif, 1/pgo
  i4 = df * qif; f4 = di * qif;
  o4 = dg * qgo;
  g4 = fmaf(dn * qgo, -2.f, 1.f);
}
// tanh of 4 RAW cell values (clamp +-8: tanh err <= 2.3e-7; product <= ~7e27, safe)
__device__ __forceinline__ void ctanh4(float c0, float c1, float c2, float c3,
                                       float& t0, float& t1, float& t2, float& t3) {
  float d0 = 1.f + ex2(__builtin_amdgcn_fmed3f(c0, -8.f, 8.f) * (2.f * L2E));
  float d1 = 1.f + ex2(__builtin_amdgcn_fmed3f(c1, -8.f, 8.f) * (2.f * L2E));
  float d2 = 1.f + ex2(__builtin_amdgcn_fmed3f(c2, -8.f, 8.f) * (2.f * L2E));
  float d3 = 1.f + ex2(__builtin_amdgcn_fmed3f(c3, -8.f, 8.f) * (2.f * L2E));
  float p01 = d0 * d1, p23 = d2 * d3;
  float rp = rcp_(p01 * p23);
  float q01 = p23 * rp, q23 = p01 * rp;
  t0 = fmaf(d1 * q01, -2.f, 1.f);
  t1 = fmaf(d0 * q01, -2.f, 1.f);
  t2 = fmaf(d3 * q23, -2.f, 1.f);
  t3 = fmaf(d2 * q23, -2.f, 1.f);
}
__device__ __forceinline__ float ctanh1(float c) {
  float d = 1.f + ex2(__builtin_amdgcn_fmed3f(c, -8.f, 8.f) * (2.f * L2E));
  return fmaf(rcp_(d), -2.f, 1.f);
}

__device__ __forceinline__ unsigned int pkbits(float lo, float hi) {
  return __builtin_bit_cast(unsigned int, __builtin_amdgcn_cvt_pkrtz(lo, hi));
}
// B fragment from this lane's own hn[5] (+ x in slot element 5): k-slot 8g+jt <-> unit 4jt+g
__device__ __forceinline__ mf16x8 mkbf(const float* hn, float xsel) {
  union { unsigned int u[4]; mf16x8 v; } cv;
  cv.u[0] = pkbits(hn[0], hn[1]);
  cv.u[1] = pkbits(hn[2], hn[3]);
  cv.u[2] = pkbits(hn[4], xsel);
  cv.u[3] = 0u;
  return cv.v;
}

// Stage one layer's weights into per-lane MFMA fragments, PRE-SCALED per gate.
// A lane (m = lane&15, ka = lane>>4): j = 16*jt + m -> unit 4*jt+(m>>2), gate m&3.
// k-slot 8*ka+kk: kk<5 -> input unit 4*kk+ka ; slot 21 -> x (Wih) ; else zero pad.
// Bias in D-layout: lane (r, g) reg i -> gate i of unit 4*jt+g.
__device__ __forceinline__ void stage_layer(
    const float* __restrict__ Wih, const float* __restrict__ Whh,
    const float* __restrict__ bih, const float* __restrict__ bhh,
    int m, int g, mf16x8* A, f32x4* Bias)
{
  const int gateA = m & 3;
  const float scA = (gateA == 2) ? (2.f * L2E) : -L2E;   // gate g vs i/f/o
#pragma unroll
  for (int jt = 0; jt < 5; ++jt) {
    const int unitA = 4 * jt + (m >> 2);
    const int trow = gateA * 20 + unitA;          // torch row in [4H]
    union { __fp16 h[8]; mf16x8 v; } av;
#pragma unroll
    for (int kk = 0; kk < 8; ++kk) {
      const int s = 8 * g + kk;
      float w = 0.f;
      if (kk < 5)       w = Whh[trow * 20 + 4 * kk + g];
      else if (s == 21) w = Wih[trow];
      av.h[kk] = (__fp16)(w * scA);
    }
    A[jt] = av.v;
    const int u = 4 * jt + g;
    f32x4 bv;
#pragma unroll
    for (int i = 0; i < 4; ++i) {
      const float sc = (i == 2) ? (2.f * L2E) : -L2E;
      bv[i] = (bih[i * 20 + u] + bhh[i * 20 + u]) * sc;
    }
    Bias[jt] = bv;
  }
}

// gate block for 5 units: 25 exp2 + 7 rcp (4-way rcp sharing)
__device__ __forceinline__ void gates5(const f32x4* a, float* c_, float* hn) {
  float i0, f0, i1, f1, i2, f2, i3, f3;
  float g0, g1, o0, o1, g2, g3, o2, o3;
  float g4, i4, f4, o4;
  sigm4(a[0][0], a[0][1], a[1][0], a[1][1], i0, f0, i1, f1);
  tanh2sigm2(a[0][2], a[1][2], a[0][3], a[1][3], g0, g1, o0, o1);
  sigm4(a[2][0], a[2][1], a[3][0], a[3][1], i2, f2, i3, f3);
  tanh2sigm2(a[2][2], a[3][2], a[2][3], a[3][3], g2, g3, o2, o3);
  tanh1sigm3(a[4][2], a[4][0], a[4][1], a[4][3], g4, i4, f4, o4);
  float c0 = fmaf(f0, c_[0], i0 * g0);
  float c1 = fmaf(f1, c_[1], i1 * g1);
  float c2 = fmaf(f2, c_[2], i2 * g2);
  float c3 = fmaf(f3, c_[3], i3 * g3);
  float c4 = fmaf(f4, c_[4], i4 * g4);
  c_[0] = c0; c_[1] = c1; c_[2] = c2; c_[3] = c3; c_[4] = c4;
  float t0, t1, t2, t3;
  ctanh4(c0, c1, c2, c3, t0, t1, t2, t3);
  float t4 = ctanh1(c4);
  hn[0] = o0 * t0; hn[1] = o1 * t1; hn[2] = o2 * t2; hn[3] = o3 * t3;
  hn[4] = o4 * t4;
}

// One full LSTM step: 5 MFMAs first (max trans ILP), then gate block.
#define STEP(A, B, bf) do {                                                         \
    f32x4 aa[5];                                                                    \
    aa[0] = __builtin_amdgcn_mfma_f32_16x16x32_f16((A)[0], bf, (B)[0], 0, 0, 0);    \
    aa[1] = __builtin_amdgcn_mfma_f32_16x16x32_f16((A)[1], bf, (B)[1], 0, 0, 0);    \
    aa[2] = __builtin_amdgcn_mfma_f32_16x16x32_f16((A)[2], bf, (B)[2], 0, 0, 0);    \
    aa[3] = __builtin_amdgcn_mfma_f32_16x16x32_f16((A)[3], bf, (B)[3], 0, 0, 0);    \
    aa[4] = __builtin_amdgcn_mfma_f32_16x16x32_f16((A)[4], bf, (B)[4], 0, 0, 0);    \
    gates5(aa, c_, hn);                                                             \
  } while (0)

extern "C" __global__ __launch_bounds__(64) void lstm_fused(
    const float* __restrict__ inp,  const float* __restrict__ Wih1,
    const float* __restrict__ Whh1, const float* __restrict__ bih1,
    const float* __restrict__ bhh1, const float* __restrict__ Wih2,
    const float* __restrict__ Whh2, const float* __restrict__ bih2,
    const float* __restrict__ bhh2, const float* __restrict__ Wl,
    const float* __restrict__ bl,   float* __restrict__ out, int Btot)
{
  __shared__ __align__(16) float ibuf[16 * IST];   // read-only input tile

  const int lane = threadIdx.x;
  const int r = lane & 15;      // batch row within the wave's 16-row tile
  const int g = lane >> 4;      // k-chunk / unit-group id
  const int row0 = blockIdx.x * 16;

  // stage input tile, coalesced
  {
    const float* src = inp + (size_t)row0 * Tt;
    for (int i = lane; i < 16 * Tt; i += 64) {
      int rr = i / Tt, t = i - rr * Tt;
      ibuf[rr * IST + t] = src[i];
    }
  }

  mf16x8 A1[5]; f32x4 B1[5];
  stage_layer(Wih1, Whh1, bih1, bhh1, r, g, A1, B1);

  float c_[5], hn[5];
#pragma unroll
  for (int jt = 0; jt < 5; ++jt) { c_[jt] = 0.f; hn[jt] = 0.f; }

  __syncthreads();

  // ================= encoder (no LDS writes, no barriers) =================
  float xt = ibuf[r * IST];
  for (int t = 0; t < Tt; ++t) {
    float xnext = (t + 1 < Tt) ? ibuf[r * IST + t + 1] : 0.f;  // prefetch
    mf16x8 bf = mkbf(hn, (g == 2) ? xt : 0.f);
    STEP(A1, B1, bf);
    xt = xnext;
  }

  // ================= log_softmax(h_e) =================
  {
    float m = hn[0];
#pragma unroll
    for (int jt = 1; jt < 5; ++jt) m = fmaxf(m, hn[jt]);
    m = fmaxf(m, __shfl_xor(m, 16, 64));
    m = fmaxf(m, __shfl_xor(m, 32, 64));
    float s = 0.f;
#pragma unroll
    for (int jt = 0; jt < 5; ++jt) s += __builtin_amdgcn_exp2f((hn[jt] - m) * L2E);
    s += __shfl_xor(s, 16, 64);
    s += __shfl_xor(s, 32, 64);
    const float lse = m + 0.69314718055994530942f * __builtin_amdgcn_logf(s);
    float* out2 = out + (size_t)Btot * Tt;
#pragma unroll
    for (int jt = 0; jt < 5; ++jt)
      out2[(size_t)(row0 + r) * 20 + 4 * jt + g] = hn[jt] - lse;
  }

  // ================= decoder =================
  mf16x8 A2[5]; f32x4 B2[5];
  stage_layer(Wih2, Whh2, bih2, bhh2, r, g, A2, B2);
  float wl[5];
#pragma unroll
  for (int jt = 0; jt < 5; ++jt) wl[jt] = Wl[4 * jt + g] * -L2E;  // pre-scaled
  const float blv = bl[0] * -L2E;

  float ot = 0.f;
  for (int s = 0; s < Tt; ++s) {
    mf16x8 bf = mkbf(hn, (g == 2) ? ot : 0.f);
    STEP(A2, B2, bf);
    float p = fmaf(hn[0], wl[0], blv);
#pragma unroll
    for (int jt = 1; jt < 5; ++jt) p = fmaf(hn[jt], wl[jt], p);
    p += __shfl_xor(p, 16, 64);
    p += __shfl_xor(p, 32, 64);
    ot = rcp_(1.f + ex2(p));  // p pre-scaled
    if (g == 0) out[(size_t)(row0 + r) * Tt + (186 - s)] = ot;    // pre-flipped store
  }
}

extern "C" void kernel_launch(void* const* d_in, const int* in_sizes, int n_in,
                              void* d_out, int out_size, void* d_ws, size_t ws_size,
                              hipStream_t stream) {
  const float* inp  = (const float*)d_in[0];
  const float* Wih1 = (const float*)d_in[1];
  const float* Whh1 = (const float*)d_in[2];
  const float* bih1 = (const float*)d_in[3];
  const float* bhh1 = (const float*)d_in[4];
  const float* Wih2 = (const float*)d_in[5];
  const float* Whh2 = (const float*)d_in[6];
  const float* bih2 = (const float*)d_in[7];
  const float* bhh2 = (const float*)d_in[8];
  const float* Wl   = (const float*)d_in[9];
  const float* bl   = (const float*)d_in[10];

  const int Btot = in_sizes[0] / Tt;   // 32768
  dim3 grid(Btot / 16), block(64);
  hipLaunchKernelGGL(lstm_fused, grid, block, 0, stream,
                     inp, Wih1, Whh1, bih1, bhh1, Wih2, Whh2, bih2, bhh2, Wl, bl,
                     (float*)d_out, Btot);
}

// Round 11
// 283.374 us; speedup vs baseline: 1.1361x; 1.0540x over previous
//
#include <hip/hip_runtime.h>

typedef __fp16 mf16x8 __attribute__((ext_vector_type(8)));
typedef float f32x4 __attribute__((ext_vector_type(4)));

#define Tt 187
#define IST 189   // ibuf row stride (f32)
#define L2E 1.44269504088896340736f

// ---- paired activations on PRE-SCALED pre-activations ----
// weights/bias rows are pre-multiplied: i,f,o by -L2E ; g by +2*L2E.
// sigm(x) = rcp(1 + exp2(x'))        with x' = -L2E*x
// tanh(x) = 1 - 2*rcp(1 + exp2(x'')) with x'' = 2*L2E*x
__device__ __forceinline__ void psigm2(float xa, float xb, float& sa, float& sb) {
  float da = 1.f + __builtin_amdgcn_exp2f(xa);
  float db = 1.f + __builtin_amdgcn_exp2f(xb);
  float rp = __builtin_amdgcn_rcpf(da * db);
  sa = db * rp;
  sb = da * rp;
}
__device__ __forceinline__ void ptanh2(float xa, float xb, float& ta, float& tb) {
  float da = 1.f + __builtin_amdgcn_exp2f(xa);
  float db = 1.f + __builtin_amdgcn_exp2f(xb);
  float rp = __builtin_amdgcn_rcpf(da * db);
  float m2 = -2.f * rp;
  ta = fmaf(db, m2, 1.f);
  tb = fmaf(da, m2, 1.f);
}
// mixed pair: tanh(g') and sigm(o') share one rcp
__device__ __forceinline__ void ptanh_sigm(float xg, float xo, float& tg, float& so) {
  float dg = 1.f + __builtin_amdgcn_exp2f(xg);
  float dn = 1.f + __builtin_amdgcn_exp2f(xo);
  float rp = __builtin_amdgcn_rcpf(dg * dn);
  tg = fmaf(dn, -2.f * rp, 1.f);
  so = dg * rp;
}
// paired tanh on RAW cell values (clamp +-16, scale 2*L2E)
__device__ __forceinline__ void ctanh2(float ca, float cb, float& ta, float& tb) {
  float xa = __builtin_amdgcn_fmed3f(ca, -16.f, 16.f) * (2.f * L2E);
  float xb = __builtin_amdgcn_fmed3f(cb, -16.f, 16.f) * (2.f * L2E);
  ptanh2(xa, xb, ta, tb);
}

__device__ __forceinline__ unsigned int pkbits(float lo, float hi) {
  return __builtin_bit_cast(unsigned int, __builtin_amdgcn_cvt_pkrtz(lo, hi));
}
// B fragment from this lane's own hn[5] (+ x in slot element 5): k-slot 8g+jt <-> unit 4jt+g
__device__ __forceinline__ mf16x8 mkbf(const float* hn, float xsel) {
  union { unsigned int u[4]; mf16x8 v; } cv;
  cv.u[0] = pkbits(hn[0], hn[1]);
  cv.u[1] = pkbits(hn[2], hn[3]);
  cv.u[2] = pkbits(hn[4], xsel);
  cv.u[3] = 0u;
  return cv.v;
}

// Stage one layer's weights into per-lane MFMA fragments, PRE-SCALED per gate.
// A lane (m = lane&15, ka = lane>>4): j = 16*jt + m -> unit 4*jt+(m>>2), gate m&3.
// k-slot 8*ka+kk: kk<5 -> input unit 4*kk+ka ; slot 21 -> x (Wih) ; else zero pad.
// Bias in D-layout: lane (r, g) reg i -> gate i of unit 4*jt+g.
__device__ __forceinline__ void stage_layer(
    const float* __restrict__ Wih, const float* __restrict__ Whh,
    const float* __restrict__ bih, const float* __restrict__ bhh,
    int m, int g, mf16x8* A, f32x4* Bias)
{
  const int gateA = m & 3;
  const float scA = (gateA == 2) ? (2.f * L2E) : -L2E;   // gate g vs i/f/o
#pragma unroll
  for (int jt = 0; jt < 5; ++jt) {
    const int unitA = 4 * jt + (m >> 2);
    const int trow = gateA * 20 + unitA;          // torch row in [4H]
    union { __fp16 h[8]; mf16x8 v; } av;
#pragma unroll
    for (int kk = 0; kk < 8; ++kk) {
      const int s = 8 * g + kk;
      float w = 0.f;
      if (kk < 5)       w = Whh[trow * 20 + 4 * kk + g];
      else if (s == 21) w = Wih[trow];
      av.h[kk] = (__fp16)(w * scA);
    }
    A[jt] = av.v;
    const int u = 4 * jt + g;
    f32x4 bv;
#pragma unroll
    for (int i = 0; i < 4; ++i) {
      const float sc = (i == 2) ? (2.f * L2E) : -L2E;
      bv[i] = (bih[i * 20 + u] + bhh[i * 20 + u]) * sc;
    }
    Bias[jt] = bv;
  }
}

// Gates for a PAIR of units (JA, JB) with pre-scaled accs; 15 trans / pair.
#define GPAIR(accA, accB, JA, JB) do {                     \
    float iA, fA, iB, fB, gA, gB, oA, oB, tA, tB;          \
    psigm2((accA)[0], (accA)[1], iA, fA);                  \
    psigm2((accB)[0], (accB)[1], iB, fB);                  \
    ptanh2((accA)[2], (accB)[2], gA, gB);                  \
    psigm2((accA)[3], (accB)[3], oA, oB);                  \
    float cA = fmaf(fA, c_[JA], iA * gA);                  \
    float cB = fmaf(fB, c_[JB], iB * gB);                  \
    c_[JA] = cA; c_[JB] = cB;                              \
    ctanh2(cA, cB, tA, tB);                                \
    hn[JA] = oA * tA; hn[JB] = oB * tB;                    \
  } while (0)

// Last unit (jt=4): i/f pair, g/o mixed pair, single c-tanh; 8 trans.
#define GLAST(acc4) do {                                               \
    float i4, f4, g4, o4;                                              \
    psigm2((acc4)[0], (acc4)[1], i4, f4);                              \
    ptanh_sigm((acc4)[2], (acc4)[3], g4, o4);                          \
    float c4 = fmaf(f4, c_[4], i4 * g4);                               \
    c_[4] = c4;                                                        \
    float s4 = __builtin_amdgcn_fmed3f(c4, -16.f, 16.f) * (2.f * L2E); \
    float d4 = 1.f + __builtin_amdgcn_exp2f(s4);                       \
    float t4 = fmaf(__builtin_amdgcn_rcpf(d4), -2.f, 1.f);             \
    hn[4] = o4 * t4;                                                   \
  } while (0)

// One full LSTM step: 5 MFMAs first (max trans ILP), then paired gates.
#define STEP(A, B, bf) do {                                                     \
    f32x4 a0 = __builtin_amdgcn_mfma_f32_16x16x32_f16((A)[0], bf, (B)[0], 0, 0, 0); \
    f32x4 a1 = __builtin_amdgcn_mfma_f32_16x16x32_f16((A)[1], bf, (B)[1], 0, 0, 0); \
    f32x4 a2 = __builtin_amdgcn_mfma_f32_16x16x32_f16((A)[2], bf, (B)[2], 0, 0, 0); \
    f32x4 a3 = __builtin_amdgcn_mfma_f32_16x16x32_f16((A)[3], bf, (B)[3], 0, 0, 0); \
    f32x4 a4 = __builtin_amdgcn_mfma_f32_16x16x32_f16((A)[4], bf, (B)[4], 0, 0, 0); \
    GPAIR(a0, a1, 0, 1);                                                        \
    GPAIR(a2, a3, 2, 3);                                                        \
    GLAST(a4);                                                                  \
  } while (0)

extern "C" __global__ __launch_bounds__(64) void lstm_fused(
    const float* __restrict__ inp,  const float* __restrict__ Wih1,
    const float* __restrict__ Whh1, const float* __restrict__ bih1,
    const float* __restrict__ bhh1, const float* __restrict__ Wih2,
    const float* __restrict__ Whh2, const float* __restrict__ bih2,
    const float* __restrict__ bhh2, const float* __restrict__ Wl,
    const float* __restrict__ bl,   float* __restrict__ out, int Btot)
{
  __shared__ __align__(16) float ibuf[16 * IST];   // read-only input tile

  const int lane = threadIdx.x;
  const int r = lane & 15;      // batch row within the wave's 16-row tile
  const int g = lane >> 4;      // k-chunk / unit-group id
  const int row0 = blockIdx.x * 16;

  // stage input tile, coalesced
  {
    const float* src = inp + (size_t)row0 * Tt;
    for (int i = lane; i < 16 * Tt; i += 64) {
      int rr = i / Tt, t = i - rr * Tt;
      ibuf[rr * IST + t] = src[i];
    }
  }

  mf16x8 A1[5]; f32x4 B1[5];
  stage_layer(Wih1, Whh1, bih1, bhh1, r, g, A1, B1);

  float c_[5], hn[5];
#pragma unroll
  for (int jt = 0; jt < 5; ++jt) { c_[jt] = 0.f; hn[jt] = 0.f; }

  __syncthreads();

  // ================= encoder (no LDS writes, no barriers) =================
  float xt = ibuf[r * IST];
  for (int t = 0; t < Tt; ++t) {
    float xnext = (t + 1 < Tt) ? ibuf[r * IST + t + 1] : 0.f;  // prefetch
    mf16x8 bf = mkbf(hn, (g == 2) ? xt : 0.f);
    STEP(A1, B1, bf);
    xt = xnext;
  }

  // ================= log_softmax(h_e) =================
  {
    float m = hn[0];
#pragma unroll
    for (int jt = 1; jt < 5; ++jt) m = fmaxf(m, hn[jt]);
    m = fmaxf(m, __shfl_xor(m, 16, 64));
    m = fmaxf(m, __shfl_xor(m, 32, 64));
    float s = 0.f;
#pragma unroll
    for (int jt = 0; jt < 5; ++jt) s += __builtin_amdgcn_exp2f((hn[jt] - m) * L2E);
    s += __shfl_xor(s, 16, 64);
    s += __shfl_xor(s, 32, 64);
    const float lse = m + 0.69314718055994530942f * __builtin_amdgcn_logf(s);
    float* out2 = out + (size_t)Btot * Tt;
#pragma unroll
    for (int jt = 0; jt < 5; ++jt)
      out2[(size_t)(row0 + r) * 20 + 4 * jt + g] = hn[jt] - lse;
  }

  // ================= decoder =================
  mf16x8 A2[5]; f32x4 B2[5];
  stage_layer(Wih2, Whh2, bih2, bhh2, r, g, A2, B2);
  float wl[5];
#pragma unroll
  for (int jt = 0; jt < 5; ++jt) wl[jt] = Wl[4 * jt + g] * -L2E;  // pre-scaled
  const float blv = bl[0] * -L2E;

  float ot = 0.f;
  for (int s = 0; s < Tt; ++s) {
    mf16x8 bf = mkbf(hn, (g == 2) ? ot : 0.f);
    STEP(A2, B2, bf);
    float p = fmaf(hn[0], wl[0], blv);
#pragma unroll
    for (int jt = 1; jt < 5; ++jt) p = fmaf(hn[jt], wl[jt], p);
    p += __shfl_xor(p, 16, 64);
    p += __shfl_xor(p, 32, 64);
    ot = __builtin_amdgcn_rcpf(1.f + __builtin_amdgcn_exp2f(p));  // p pre-scaled
    if (g == 0) out[(size_t)(row0 + r) * Tt + (186 - s)] = ot;    // pre-flipped store
  }
}

extern "C" void kernel_launch(void* const* d_in, const int* in_sizes, int n_in,
                              void* d_out, int out_size, void* d_ws, size_t ws_size,
                              hipStream_t stream) {
  const float* inp  = (const float*)d_in[0];
  const float* Wih1 = (const float*)d_in[1];
  const float* Whh1 = (const float*)d_in[2];
  const float* bih1 = (const float*)d_in[3];
  const float* bhh1 = (const float*)d_in[4];
  const float* Wih2 = (const float*)d_in[5];
  const float* Whh2 = (const float*)d_in[6];
  const float* bih2 = (const float*)d_in[7];
  const float* bhh2 = (const float*)d_in[8];
  const float* Wl   = (const float*)d_in[9];
  const float* bl   = (const float*)d_in[10];

  const int Btot = in_sizes[0] / Tt;   // 32768
  dim3 grid(Btot / 16), block(64);
  hipLaunchKernelGGL(lstm_fused, grid, block, 0, stream,
                     inp, Wih1, Whh1, bih1, bhh1, Wih2, Whh2, bih2, bhh2, Wl, bl,
                     (float*)d_out, Btot);
}